// Round 1
// baseline (212.800 us; speedup 1.0000x reference)
//
#include <hip/hip_runtime.h>

#define DIMN 192
#define SD (DIMN * DIMN)            // plane stride (floats)
#define CS (DIMN * DIMN * DIMN)     // channel stride (floats)
#define NCH_D 4                     // d-chunks in K3
#define DCH (DIMN / NCH_D)          // 48
#define NPART (DIMN * NCH_D)        // 768 partials

// ---------------------------------------------------------------------------
// K1: W-pass. grid = 192*192 blocks (one per (d,h) row), block = 192 threads.
// Computes 9-tap zero-padded sliding sums along W of {I, J, I*I, J*J, I*J}.
// ---------------------------------------------------------------------------
__global__ void k1_wpass(const float* __restrict__ I, const float* __restrict__ J,
                         float* __restrict__ buf) {
    __shared__ float si[DIMN];
    __shared__ float sj[DIMN];
    const int bid = blockIdx.x;
    const int d = bid / DIMN, h = bid % DIMN;
    const int w = threadIdx.x;
    const int base = d * SD + h * DIMN;
    const float iv = I[base + w];
    const float jv = J[base + w];
    si[w] = iv;
    sj[w] = jv;
    __syncthreads();
    float s0 = 0.f, s1 = 0.f, s2 = 0.f, s3 = 0.f, s4 = 0.f;
#pragma unroll
    for (int k = -4; k <= 4; k++) {
        const int ww = w + k;
        if (ww >= 0 && ww < DIMN) {
            const float a = si[ww], b = sj[ww];
            s0 += a;
            s1 += b;
            s2 += a * a;
            s3 += b * b;
            s4 += a * b;
        }
    }
    buf[0 * CS + base + w] = s0;
    buf[1 * CS + base + w] = s1;
    buf[2 * CS + base + w] = s2;
    buf[3 * CS + base + w] = s3;
    buf[4 * CS + base + w] = s4;
}

// ---------------------------------------------------------------------------
// K2: H-pass, in place. grid = 5*192 blocks (one per (q,d) plane),
// block = 192 threads (one per w column). Sliding window along h with a
// fully-unrolled 9-register shift ring (static indices -> stays in VGPRs).
// In-place safe: at iter h we write row h, read row h+5 (not yet written);
// the subtracted row h-4 comes from the register ring.
// ---------------------------------------------------------------------------
__global__ void k2_hpass(float* __restrict__ buf) {
    const int bid = blockIdx.x;
    const int q = bid / DIMN, d = bid % DIMN;
    const int w = threadIdx.x;
    float* p = buf + q * CS + d * SD + w;

    float win[9];
    float run = 0.f;
#pragma unroll
    for (int k = 0; k < 9; k++) {
        const int hh = k - 4;                        // rows -4..4
        const float v = (hh >= 0) ? p[hh * DIMN] : 0.f;
        win[k] = v;
        run += v;
    }
    for (int h = 0; h < DIMN; h++) {
        p[h * DIMN] = run;
        const int hn = h + 5;
        const float v = (hn < DIMN) ? p[hn * DIMN] : 0.f;
        run += v - win[0];
#pragma unroll
        for (int k = 0; k < 8; k++) win[k] = win[k + 1];
        win[8] = v;
    }
}

// ---------------------------------------------------------------------------
// K3: D-pass + cc + partial reduction. grid = 192*NCH_D blocks, block = 192.
// Each block handles one h and one d-chunk of 48 outputs; thread = w column.
// Sliding window along d for the 5 channels (re-reads add/sub taps; buffer is
// read-only here so chunk halos are race-free). cc computed in the reference's
// exact f32 expression order; accumulated in double.
// ---------------------------------------------------------------------------
__global__ void k3_dpass(const float* __restrict__ buf, double* __restrict__ partials) {
    const int bid = blockIdx.x;
    const int h = bid / NCH_D;
    const int d0 = (bid % NCH_D) * DCH;
    const int w = threadIdx.x;
    const float* p = buf + h * DIMN + w;

    float run[5];
#pragma unroll
    for (int q = 0; q < 5; q++) run[q] = 0.f;
#pragma unroll
    for (int k = -4; k <= 4; k++) {
        const int dd = d0 + k;
        if (dd >= 0 && dd < DIMN) {
#pragma unroll
            for (int q = 0; q < 5; q++) run[q] += p[q * CS + dd * SD];
        }
    }

    double acc = 0.0;
    for (int d = d0; d < d0 + DCH; d++) {
        const float s0 = run[0], s1 = run[1], s2 = run[2], s3 = run[3], s4 = run[4];
        const float u_I = s0 / 729.0f;
        const float u_J = s1 / 729.0f;
        const float cross = s4 - u_J * s0 - u_I * s1 + u_I * u_J * 729.0f;
        const float I_var = s2 - 2.0f * u_I * s0 + u_I * u_I * 729.0f;
        const float J_var = s3 - 2.0f * u_J * s1 + u_J * u_J * 729.0f;
        const float cc = cross * cross / (I_var * J_var + 1e-5f);
        acc += (double)cc;

        const int da = d + 5, ds = d - 4;
#pragma unroll
        for (int q = 0; q < 5; q++) {
            const float va = (da < DIMN) ? p[q * CS + da * SD] : 0.f;
            const float vs = (ds >= 0) ? p[q * CS + ds * SD] : 0.f;
            run[q] += va - vs;
        }
    }

    // block reduction: 192 threads = 3 waves
    __shared__ double wsum[3];
#pragma unroll
    for (int off = 32; off > 0; off >>= 1) acc += __shfl_down(acc, off, 64);
    const int lane = threadIdx.x & 63;
    const int wv = threadIdx.x >> 6;
    if (lane == 0) wsum[wv] = acc;
    __syncthreads();
    if (threadIdx.x == 0) partials[bid] = wsum[0] + wsum[1] + wsum[2];
}

// ---------------------------------------------------------------------------
// K4: final reduction of NPART doubles -> out[0] = -(mean cc). 1 block, 256.
// ---------------------------------------------------------------------------
__global__ void k4_final(const double* __restrict__ partials, float* __restrict__ out) {
    __shared__ double wsum[4];
    double acc = 0.0;
    for (int i = threadIdx.x; i < NPART; i += 256) acc += partials[i];
#pragma unroll
    for (int off = 32; off > 0; off >>= 1) acc += __shfl_down(acc, off, 64);
    const int lane = threadIdx.x & 63;
    const int wv = threadIdx.x >> 6;
    if (lane == 0) wsum[wv] = acc;
    __syncthreads();
    if (threadIdx.x == 0) {
        const double total = wsum[0] + wsum[1] + wsum[2] + wsum[3];
        out[0] = -(float)(total / (double)CS);
    }
}

extern "C" void kernel_launch(void* const* d_in, const int* in_sizes, int n_in,
                              void* d_out, int out_size, void* d_ws, size_t ws_size,
                              hipStream_t stream) {
    const float* I = (const float*)d_in[0];   // y_true
    const float* J = (const float*)d_in[1];   // y_pred
    float* buf = (float*)d_ws;                                        // 5 * 192^3 f32
    double* partials = (double*)((char*)d_ws + (size_t)5 * CS * sizeof(float));
    float* out = (float*)d_out;

    hipLaunchKernelGGL(k1_wpass, dim3(DIMN * DIMN), dim3(DIMN), 0, stream, I, J, buf);
    hipLaunchKernelGGL(k2_hpass, dim3(5 * DIMN), dim3(DIMN), 0, stream, buf);
    hipLaunchKernelGGL(k3_dpass, dim3(DIMN * NCH_D), dim3(DIMN), 0, stream, buf, partials);
    hipLaunchKernelGGL(k4_final, dim3(1), dim3(256), 0, stream, partials, out);
}